// Round 5
// baseline (513.237 us; speedup 1.0000x reference)
//
#include <hip/hip_runtime.h>
#include <hip/hip_bf16.h>

// Problem constants
#define Bb 2
#define Ss 2048
#define Ee 2048
#define Hh 16
#define Dd 128
#define Mrows (Bb*Ss)   // 4096

typedef short short8 __attribute__((ext_vector_type(8)));
typedef float f32x4 __attribute__((ext_vector_type(4)));

__device__ __forceinline__ unsigned short bf_rne(float f) {
    unsigned u = __builtin_bit_cast(unsigned, f);
    u += 0x7fffu + ((u >> 16) & 1u);
    return (unsigned short)(u >> 16);
}
__device__ __forceinline__ float bf2f(unsigned short x) {
    unsigned u = ((unsigned)x) << 16;
    return __builtin_bit_cast(float, u);
}
__device__ __forceinline__ unsigned pack_bf2(float a, float b) {
    return (unsigned)bf_rne(a) | ((unsigned)bf_rne(b) << 16);
}
__device__ __forceinline__ void load_lds16(const void* g, void* l) {
    __builtin_amdgcn_global_load_lds(
        (const __attribute__((address_space(1))) unsigned int*)g,
        (__attribute__((address_space(3))) unsigned int*)l, 16, 0, 0);
}

// ---------------- fused fp32 -> bf16 cast of all 6 tensors ----------------
__global__ void cast_all_kernel(const float4* __restrict__ xq, const float4* __restrict__ xkv,
                                const float4* __restrict__ wq, const float4* __restrict__ wk,
                                const float4* __restrict__ wv, const float4* __restrict__ wo,
                                ushort4* __restrict__ out) {
    int i = blockIdx.x * 256 + threadIdx.x;
    const float4* src;
    int rel;
    if (i < 2097152)       { src = xq;  rel = i; }
    else if (i < 4194304)  { src = xkv; rel = i - 2097152; }
    else if (i < 5242880)  { src = wq;  rel = i - 4194304; }
    else if (i < 6291456)  { src = wk;  rel = i - 5242880; }
    else if (i < 7340032)  { src = wv;  rel = i - 6291456; }
    else                   { src = wo;  rel = i - 7340032; }
    float4 v = src[rel];
    ushort4 o;
    o.x = bf_rne(v.x); o.y = bf_rne(v.y); o.z = bf_rne(v.z); o.w = bf_rne(v.w);
    out[i] = o;
}

// ---------------- shared GEMM core: 128x128 tile, BK=64, XOR-swizzled LDS ----------------
__device__ __forceinline__ void gemm_core(
    const short* __restrict__ A, const short* __restrict__ W, int K,
    int m0, int n0, int wave, int lane, short* As, short* Bs, f32x4 acc[4][4])
{
    const int wm = (wave & 1) * 64;
    const int wn = (wave >> 1) * 64;
    const int quad = lane >> 4;
    const int l16  = lane & 15;
    const int lrow   = lane >> 3;
    const int gchunk = (lane & 7) ^ lrow;

    for (int kt = 0; kt < K; kt += 64) {
        __syncthreads();
        #pragma unroll
        for (int j = 0; j < 4; ++j) {
            int row = wave*32 + j*8 + lrow;
            load_lds16(A + (size_t)(m0 + row)*K + kt + gchunk*8, &As[(wave*32 + j*8)*64]);
            load_lds16(W + (size_t)(n0 + row)*K + kt + gchunk*8, &Bs[(wave*32 + j*8)*64]);
        }
        __syncthreads();

        #pragma unroll
        for (int ks = 0; ks < 64; ks += 32) {
            const int cs = ks >> 3;
            short8 af[4], bfr[4];
            #pragma unroll
            for (int i = 0; i < 4; ++i)
                af[i] = *(const short8*)&As[(wm + i*16 + l16)*64 + (((cs + quad) ^ (l16 & 7)) << 3)];
            #pragma unroll
            for (int j = 0; j < 4; ++j)
                bfr[j] = *(const short8*)&Bs[(wn + j*16 + l16)*64 + (((cs + quad) ^ (l16 & 7)) << 3)];
            #pragma unroll
            for (int i = 0; i < 4; ++i)
                #pragma unroll
                for (int j = 0; j < 4; ++j)
                    acc[i][j] = __builtin_amdgcn_mfma_f32_16x16x32_bf16(af[i], bfr[j], acc[i][j], 0, 0, 0);
        }
    }
}

union GemmSmem {
    struct { short As[128*64]; short Bs[128*64]; } st;
    short T[128*137];
};

// ---------------- fused QKV projection ----------------
__global__ __launch_bounds__(256) void qkv_gemm(
    const short* __restrict__ xq, const short* __restrict__ xkv,
    const short* __restrict__ wq, const short* __restrict__ wk, const short* __restrict__ wv,
    const float* __restrict__ bq, const float* __restrict__ bk, const float* __restrict__ bv,
    short* __restrict__ Qr, short* __restrict__ Kr, short* __restrict__ VT)
{
    __shared__ GemmSmem sm;
    const int tid  = threadIdx.x;
    const int wave = tid >> 6;
    const int lane = tid & 63;
    const int quad = lane >> 4;
    const int l16  = lane & 15;
    const int m0   = blockIdx.x * 128;
    const int sub  = blockIdx.y >> 4;
    const int nb   = blockIdx.y & 15;
    const int n0   = nb * 128;
    const int wm = (wave & 1) * 64;
    const int wn = (wave >> 1) * 64;

    const short* A = (sub == 0) ? xq : xkv;
    const short* W = (sub == 0) ? wq : (sub == 1) ? wk : wv;
    const float* bias = (sub == 0) ? bq : (sub == 1) ? bk : bv;

    f32x4 acc[4][4] = {};
    gemm_core(A, W, Ee, m0, n0, wave, lane, sm.st.As, sm.st.Bs, acc);

    const int b0 = m0 >> 11;
    const int s0 = m0 & (Ss - 1);

    if (sub < 2) {
        short* out = (sub == 0) ? Qr : Kr;
        #pragma unroll
        for (int i = 0; i < 4; ++i)
            #pragma unroll
            for (int j = 0; j < 4; ++j)
                #pragma unroll
                for (int r = 0; r < 4; ++r) {
                    int gm = m0 + wm + i*16 + quad*4 + r;
                    int gn = n0 + wn + j*16 + l16;
                    float v = acc[i][j][r] + bias[gn];
                    int b = gm >> 11, s = gm & (Ss-1);
                    int h = gn >> 7,  d = gn & (Dd-1);
                    out[(((size_t)(b*Hh + h)) * Ss + s) * Dd + d] = (short)bf_rne(v);
                }
    } else {
        __syncthreads();
        #pragma unroll
        for (int i = 0; i < 4; ++i)
            #pragma unroll
            for (int j = 0; j < 4; ++j)
                #pragma unroll
                for (int r = 0; r < 4; ++r) {
                    int ml = wm + i*16 + quad*4 + r;
                    int nl = wn + j*16 + l16;
                    sm.T[ml*137 + nl] = (short)bf_rne(acc[i][j][r] + bias[n0 + nl]);
                }
        __syncthreads();
        const int g = tid & 15, dbase = tid >> 4;
        const int h = nb;
        #pragma unroll
        for (int dd = 0; dd < 8; ++dd) {
            int d = dbase + dd*16;
            short8 v;
            #pragma unroll
            for (int c = 0; c < 8; ++c)
                v[c] = sm.T[(g*8 + c)*137 + d];
            *(short8*)&VT[(((size_t)(b0*Hh + h)) * Dd + d) * Ss + s0 + g*8] = v;
        }
    }
}

// ---------------- O-projection ----------------
__global__ __launch_bounds__(256) void oproj_gemm(
    const short* __restrict__ A, const short* __restrict__ W,
    const float* __restrict__ bias, float* __restrict__ Cf)
{
    __shared__ GemmSmem sm;
    const int tid  = threadIdx.x;
    const int wave = tid >> 6;
    const int lane = tid & 63;
    const int quad = lane >> 4;
    const int l16  = lane & 15;
    const int m0 = blockIdx.x * 128;
    const int n0 = blockIdx.y * 128;
    const int wm = (wave & 1) * 64;
    const int wn = (wave >> 1) * 64;

    f32x4 acc[4][4] = {};
    gemm_core(A, W, Ee, m0, n0, wave, lane, sm.st.As, sm.st.Bs, acc);

    #pragma unroll
    for (int i = 0; i < 4; ++i)
        #pragma unroll
        for (int j = 0; j < 4; ++j)
            #pragma unroll
            for (int r = 0; r < 4; ++r) {
                int gm = m0 + wm + i*16 + quad*4 + r;
                int gn = n0 + wn + j*16 + l16;
                Cf[(size_t)gm * Ee + gn] = acc[i][j][r] + bias[gn];
            }
}

// ---------------- RoPE (Q gets 1/sqrt(D)*log2(e) folded; K plain) ----------------
__global__ void rope_kernel(short* __restrict__ Qr, short* __restrict__ Kr,
                            const float* __restrict__ cosT, const float* __restrict__ sinT) {
    short* X    = blockIdx.y ? Kr : Qr;
    float scale = blockIdx.y ? 1.0f : 0.1275174253055484f;  // log2(e)/sqrt(128)
    int idx = blockIdx.x * 256 + threadIdx.x;
    int d  = idx & 63;
    int s  = (idx >> 6) & (Ss - 1);
    int bh = idx >> 17;
    size_t base = ((size_t)bh * Ss + s) * Dd;
    float x1 = bf2f((unsigned short)X[base + d]);
    float x2 = bf2f((unsigned short)X[base + d + 64]);
    float c  = cosT[s*Dd + d];
    float sn = sinT[s*Dd + d];
    X[base + d]      = (short)bf_rne((x1 * c - x2 * sn) * scale);
    X[base + d + 64] = (short)bf_rne((x2 * c + x1 * sn) * scale);
}

// ---------------- Flash attention (causal): S^T formulation ----------------
// Computes S^T = K Q^T (C/D: lane=q, quad*4+r=k), softmax stats per-lane,
// P^T built as PV B-operand via cross-quad bpermute (no LDS round trip),
// O^T accumulated via mfma(A=V^T, B=P^T). LDS = 48 KB -> 3 blocks/CU.
__global__ __launch_bounds__(256, 3) void attn_kernel(
    const short* __restrict__ Q, const short* __restrict__ Kk,
    const short* __restrict__ VT, short* __restrict__ O)
{
    __shared__ short Ks[64*128];        // 16 KB, chunk c at c^(row&15)
    __shared__ short Vt[2][128*64];     // 32 KB, chunk c at c^(row&7)

    const int tid  = threadIdx.x;
    const int wave = tid >> 6;
    const int lane = tid & 63;
    const int quad = lane >> 4;
    const int l16  = lane & 15;
    const int mmap = (blockIdx.x + blockIdx.y) & 15;
    const int qt   = (blockIdx.y & 16) ? (15 - mmap) : mmap;
    const int bh = blockIdx.y;
    const int b  = bh >> 4, h = bh & 15;
    const size_t head_off = (size_t)bh * Ss * Dd;
    const short* Kg  = Kk + head_off;
    const short* VTg = VT + head_off;

    auto stageK = [&](int kt) {
        #pragma unroll
        for (int j = 0; j < 4; ++j) {
            int r = wave*16 + j*4 + (lane >> 4);
            int c = (lane & 15) ^ (r & 15);
            load_lds16(Kg + (size_t)(kt*64 + r)*Dd + c*8, &Ks[(wave*16 + j*4)*128]);
        }
    };
    auto stageV = [&](int kt, int buf) {
        #pragma unroll
        for (int j = 0; j < 4; ++j) {
            int r = wave*32 + j*8 + (lane >> 3);
            int c = (lane & 7) ^ (r & 7);
            load_lds16(VTg + (size_t)r*Ss + kt*64 + c*8, &Vt[buf][(wave*32 + j*8)*64]);
        }
    };

    // Q as B-operand: lane n=l16=q, k(d)=quad*8+j
    const int qw = qt*128 + wave*32;
    short8 qb[2][4];
    #pragma unroll
    for (int qf = 0; qf < 2; ++qf)
        #pragma unroll
        for (int ds = 0; ds < 4; ++ds)
            qb[qf][ds] = *(const short8*)&Q[head_off + (size_t)(qw + qf*16 + l16)*Dd + ds*32 + quad*8];

    f32x4 o[8][2] = {};                 // O^T frags [dt][qf]
    float m_i[2] = {-__builtin_inff(), -__builtin_inff()};
    float l_i[2] = {0.f, 0.f};

    const int ktiles = 2*qt + 2;
    stageK(0);
    stageV(0, 0);

    for (int kt = 0; kt < ktiles; ++kt) {
        __syncthreads();
        if (kt + 1 < ktiles) stageV(kt+1, (kt+1)&1);

        // S^T = K Q^T : A-frag = K rows from Ks (m=k-row), B = qb
        f32x4 sc[4][2] = {};
        #pragma unroll
        for (int kf = 0; kf < 4; ++kf)
            #pragma unroll
            for (int ds = 0; ds < 4; ++ds) {
                short8 af = *(const short8*)&Ks[(kf*16 + l16)*128 + (((ds*4 + quad) ^ l16) * 8)];
                #pragma unroll
                for (int qf = 0; qf < 2; ++qf)
                    sc[kf][qf] = __builtin_amdgcn_mfma_f32_16x16x32_bf16(af, qb[qf][ds], sc[kf][qf], 0, 0, 0);
            }

        __syncthreads();
        if (kt + 1 < ktiles) stageK(kt+1);

        const int k0 = kt*64;
        // causal mask: k = k0+kf*16+quad*4+r (row), q = qw+qf*16+l16 (lane)
        if (k0 + 63 > qw) {
            #pragma unroll
            for (int kf = 0; kf < 4; ++kf)
                #pragma unroll
                for (int qf = 0; qf < 2; ++qf) {
                    int kg = k0 + kf*16 + quad*4;
                    int qg = qw + qf*16 + l16;
                    #pragma unroll
                    for (int r = 0; r < 4; ++r)
                        if (kg + r > qg) sc[kf][qf][r] = -__builtin_inff();
                }
        }

        // online softmax per q (lane-resident): cross-quad max, per-lane partial sum
        float alpha[2];
        #pragma unroll
        for (int qf = 0; qf < 2; ++qf) {
            float mx = -__builtin_inff();
            #pragma unroll
            for (int kf = 0; kf < 4; ++kf)
                #pragma unroll
                for (int r = 0; r < 4; ++r)
                    mx = fmaxf(mx, sc[kf][qf][r]);
            mx = fmaxf(mx, __shfl_xor(mx, 16));
            mx = fmaxf(mx, __shfl_xor(mx, 32));
            float mn = fmaxf(m_i[qf], mx);
            alpha[qf] = __builtin_amdgcn_exp2f(m_i[qf] - mn);
            m_i[qf] = mn;
            float s = 0.f;
            #pragma unroll
            for (int kf = 0; kf < 4; ++kf)
                #pragma unroll
                for (int r = 0; r < 4; ++r) {
                    float p = __builtin_amdgcn_exp2f(sc[kf][qf][r] - mn);
                    sc[kf][qf][r] = p;
                    s += p;
                }
            l_i[qf] = l_i[qf] * alpha[qf] + s;   // quad-partial; reduced in epilogue
        }

        // pack P to bf16 pairs: pk[kf][qf][pair] (pair0 = r0,r1 ; pair1 = r2,r3)
        unsigned pk[4][2][2];
        #pragma unroll
        for (int kf = 0; kf < 4; ++kf)
            #pragma unroll
            for (int qf = 0; qf < 2; ++qf) {
                pk[kf][qf][0] = pack_bf2(sc[kf][qf][0], sc[kf][qf][1]);
                pk[kf][qf][1] = pack_bf2(sc[kf][qf][2], sc[kf][qf][3]);
            }

        // rescale O^T by alpha (lane-uniform per q)
        #pragma unroll
        for (int dt = 0; dt < 8; ++dt)
            #pragma unroll
            for (int qf = 0; qf < 2; ++qf)
                #pragma unroll
                for (int r = 0; r < 4; ++r)
                    o[dt][qf][r] *= alpha[qf];

        // PV: O^T += V^T * P^T.  Build P^T B-frags via cross-quad bpermute:
        // dst (quad,kk,j): k = kk*32+quad*8+j  <-  src frag kf=kk*2+(quad>>1),
        // src quad = (quad&1)*2 + (j>>2), pair = (j>>1)&1.
        const short* vb = Vt[kt & 1];
        const int src0 = ((quad & 1) * 2) * 16 + l16;
        const int src1 = src0 + 16;
        #pragma unroll
        for (int kk = 0; kk < 2; ++kk) {
            short8 pb[2];
            #pragma unroll
            for (int qf = 0; qf < 2; ++qf) {
                unsigned a0 = __shfl((int)pk[kk*2][qf][0],   src0);
                unsigned a1 = __shfl((int)pk[kk*2][qf][1],   src0);
                unsigned a2 = __shfl((int)pk[kk*2][qf][0],   src1);
                unsigned a3 = __shfl((int)pk[kk*2][qf][1],   src1);
                unsigned b0 = __shfl((int)pk[kk*2+1][qf][0], src0);
                unsigned b1 = __shfl((int)pk[kk*2+1][qf][1], src0);
                unsigned b2 = __shfl((int)pk[kk*2+1][qf][0], src1);
                unsigned b3 = __shfl((int)pk[kk*2+1][qf][1], src1);
                uint4 dw;
                dw.x = (quad < 2) ? a0 : b0;
                dw.y = (quad < 2) ? a1 : b1;
                dw.z = (quad < 2) ? a2 : b2;
                dw.w = (quad < 2) ? a3 : b3;
                pb[qf] = __builtin_bit_cast(short8, dw);
            }
            #pragma unroll
            for (int dt = 0; dt < 8; ++dt) {
                short8 vf = *(const short8*)&vb[(dt*16 + l16)*64 + (((kk*4 + quad) ^ (l16 & 7)) * 8)];
                #pragma unroll
                for (int qf = 0; qf < 2; ++qf)
                    o[dt][qf] = __builtin_amdgcn_mfma_f32_16x16x32_bf16(vf, pb[qf], o[dt][qf], 0, 0, 0);
            }
        }
    }

    // epilogue: reduce l across quads, store O[q][d] (lane=q, 8B chunks per dt)
    #pragma unroll
    for (int qf = 0; qf < 2; ++qf) {
        float l = l_i[qf];
        l += __shfl_xor(l, 16);
        l += __shfl_xor(l, 32);
        float inv = 1.0f / l;
        int q = qw + qf*16 + l16;
        size_t obase = ((size_t)b * Ss + q) * Ee + h * Dd + quad*4;
        #pragma unroll
        for (int dt = 0; dt < 8; ++dt) {
            short4 v;
            v.x = (short)bf_rne(o[dt][qf][0] * inv);
            v.y = (short)bf_rne(o[dt][qf][1] * inv);
            v.z = (short)bf_rne(o[dt][qf][2] * inv);
            v.w = (short)bf_rne(o[dt][qf][3] * inv);
            *(short4*)&O[obase + dt*16] = v;
        }
    }
}

extern "C" void kernel_launch(void* const* d_in, const int* in_sizes, int n_in,
                              void* d_out, int out_size, void* d_ws, size_t ws_size,
                              hipStream_t stream) {
    const float* x_q  = (const float*)d_in[0];
    const float* x_kv = (const float*)d_in[1];
    const float* cosT = (const float*)d_in[2];
    const float* sinT = (const float*)d_in[3];
    const float* wq = (const float*)d_in[4];
    const float* bq = (const float*)d_in[5];
    const float* wk = (const float*)d_in[6];
    const float* bk = (const float*)d_in[7];
    const float* wv = (const float*)d_in[8];
    const float* bv = (const float*)d_in[9];
    const float* wo = (const float*)d_in[10];
    const float* bo = (const float*)d_in[11];

    size_t off = 0;
    auto alloc = [&](size_t bytes) {
        void* p = (char*)d_ws + off;
        off += (bytes + 255) & ~(size_t)255;
        return p;
    };
    const size_t nX = (size_t)Mrows * Ee;
    const size_t nW = (size_t)Ee * Ee;
    short* xq16  = (short*)alloc(nX * 2);
    short* xkv16 = (short*)alloc(nX * 2);
    short* wq16  = (short*)alloc(nW * 2);
    short* wk16  = (short*)alloc(nW * 2);
    short* wv16  = (short*)alloc(nW * 2);
    short* wo16  = (short*)alloc(nW * 2);
    short* Qr    = (short*)alloc(nX * 2);      // [B,H,S,D]
    short* Kr    = (short*)alloc(nX * 2);      // [B,H,S,D]
    short* VTb   = (short*)alloc(nX * 2);      // [B,H,D,S]
    short* Ob    = (short*)alloc(nX * 2);      // [B,S,E]

    cast_all_kernel<<<32768, 256, 0, stream>>>(
        (const float4*)x_q, (const float4*)x_kv, (const float4*)wq,
        (const float4*)wk, (const float4*)wv, (const float4*)wo, (ushort4*)xq16);

    qkv_gemm<<<dim3(Mrows/128, 48), 256, 0, stream>>>(
        xq16, xkv16, wq16, wk16, wv16, bq, bk, bv, Qr, Kr, VTb);

    rope_kernel<<<dim3((Bb*Hh*Ss*64)/256, 2), 256, 0, stream>>>(Qr, Kr, cosT, sinT);

    attn_kernel<<<dim3(16, Bb*Hh), 256, 0, stream>>>(Qr, Kr, VTb, Ob);

    oproj_gemm<<<dim3(Mrows/128, Ee/128), 256, 0, stream>>>(Ob, wo16, bo, (float*)d_out);
}